// Round 8
// baseline (1181.172 us; speedup 1.0000x reference)
//
#include <hip/hip_runtime.h>
#include <stdint.h>

typedef short bf16x8 __attribute__((ext_vector_type(8)));
typedef float f32x4 __attribute__((ext_vector_type(4)));
typedef unsigned short u16;

__device__ __forceinline__ float b2f(u16 u) {
  return __uint_as_float(((unsigned)u) << 16);
}
__device__ __forceinline__ u16 f2b(float f) {
  unsigned u = __float_as_uint(f);
  return (u16)((u + 0x7fffu + ((u >> 16) & 1u)) >> 16);  // RNE
}

#define NEGINF (-1.0e30f)

__device__ __forceinline__ void gld_lds16(const u16* g, u16* l) {
  __builtin_amdgcn_global_load_lds(
      (const __attribute__((address_space(1))) unsigned int*)(const void*)g,
      (__attribute__((address_space(3))) unsigned int*)(void*)l, 16, 0, 0);
}

// ---------------------------------------------------------------- dtype sniff
// flags[i]=1 -> input i is fp32 (detected from raw u16 stream signatures).
__global__ void sniff5(const u16* x, const u16* wq, const u16* wo,
                       const u16* qg, const u16* kg, int* flags) {
  const u16* p;
  int S;
  switch (blockIdx.x) {
    case 0: p = x;  S = 2048; break;
    case 1: p = wq; S = 2048; break;
    case 2: p = wo; S = 2048; break;
    case 3: p = qg; S = 128;  break;
    default: p = kg; S = 128; break;
  }
  __shared__ int cbig, czero;
  if (threadIdx.x == 0) { cbig = 0; czero = 0; }
  __syncthreads();
  int cb = 0, cz = 0;
  for (int i = threadIdx.x; i < S; i += 256) {
    const u16 u = p[i];
    if (((u >> 7) & 0xFF) >= 0xC0) ++cb;
    if (!(i & 1) && u == 0) ++cz;
  }
  atomicAdd(&cbig, cb);
  atomicAdd(&czero, cz);
  __syncthreads();
  if (threadIdx.x == 0)
    flags[blockIdx.x] = (cbig > S / 32 || czero > 3 * S / 8) ? 1 : 0;
}

// ---------------------------------------------------------------- convert
__global__ __launch_bounds__(256) void conv_in(const void* __restrict__ src,
                                               u16* __restrict__ dst,
                                               const int* __restrict__ flags,
                                               int fidx, int n) {
  const int fp32 = flags[fidx];
  int i = blockIdx.x * 256 + threadIdx.x;
  const int stride = gridDim.x * 256;
  if (fp32) {
    const float* s = (const float*)src;
    for (; i < n; i += stride) dst[i] = f2b(s[i]);
  } else {
    const u16* s = (const u16*)src;
    for (; i < n; i += stride) dst[i] = s[i];
  }
}

// ---------------------------------------------------------------- transpose_in
// dst[c][r] = bf16(src[r*ss + c]); dual-dtype. 64x64 tiles.
__global__ __launch_bounds__(256) void transpose_in(
    const void* __restrict__ src, u16* __restrict__ dst,
    const int* __restrict__ flags, int fidx, int ss, int ds) {
  __shared__ u16 tile[64][65];
  const int fp32 = flags[fidx];
  const int rb = blockIdx.y * 64, cb = blockIdx.x * 64;
  const int cl = threadIdx.x & 63, r0 = threadIdx.x >> 6;
  if (fp32) {
    const float* s = (const float*)src;
#pragma unroll
    for (int i = 0; i < 16; ++i) {
      int r = r0 + i * 4;
      tile[r][cl] = f2b(s[(long long)(rb + r) * ss + cb + cl]);
    }
  } else {
    const u16* s = (const u16*)src;
#pragma unroll
    for (int i = 0; i < 16; ++i) {
      int r = r0 + i * 4;
      tile[r][cl] = s[(long long)(rb + r) * ss + cb + cl];
    }
  }
  __syncthreads();
#pragma unroll
  for (int i = 0; i < 16; ++i) {
    int r2 = r0 + i * 4;
    dst[(long long)(cb + r2) * ds + rb + cl] = tile[cl][r2];
  }
}

// ---------------------------------------------------------------- transpose
__global__ __launch_bounds__(256) void transpose_bf16(
    const u16* __restrict__ src, u16* __restrict__ dst, int ss, int ds,
    long long sz, long long dz) {
  __shared__ u16 tile[64][65];
  const u16* s = src + (long long)blockIdx.z * sz;
  u16* d = dst + (long long)blockIdx.z * dz;
  const int rb = blockIdx.y * 64, cb = blockIdx.x * 64;
  const int cl = threadIdx.x & 63, r0 = threadIdx.x >> 6;
#pragma unroll
  for (int i = 0; i < 16; ++i) {
    int r = r0 + i * 4;
    tile[r][cl] = s[(long long)(rb + r) * ss + cb + cl];
  }
  __syncthreads();
#pragma unroll
  for (int i = 0; i < 16; ++i) {
    int r2 = r0 + i * 4;
    d[(long long)(cb + r2) * ds + rb + cl] = tile[cl][r2];
  }
}

// ---------------------------------------------------------------- fused QKV GEMM
// C(4096 x 6144) = A(4096x2048) * Bt(6144x2048)^T, split into q/k/v outputs
// (each 4096x2048, ldc 2048). 128x128 tile, BK=32, gld_lds width-16 staging
// with T2 chunk swizzle. 1536 flat blocks; XCD slab mapping: xcd=bid&7 owns
// n-blocks [xcd*6, xcd*6+6) -> per-XCD B working set 3.1 MB (L2-resident).
__global__ __launch_bounds__(256) void gemm_qkv(
    const u16* __restrict__ A, const u16* __restrict__ Bt,
    u16* __restrict__ Cq, u16* __restrict__ Ck, u16* __restrict__ Cv, int K) {
  __shared__ __align__(16) u16 As[128 * 32];
  __shared__ __align__(16) u16 Bs[128 * 32];
  const int bid = blockIdx.x;
  const int xcd = bid & 7, lid = bid >> 3;      // lid in [0,192)
  const int mb = lid / 6, nsub = lid - mb * 6;  // mb [0,32), nsub [0,6)
  const int nb = xcd * 6 + nsub;                // [0,48)
  const int m0 = mb * 128;
  const int n0g = nb * 128;                     // Bt row base (0..6143)
  const int sel = nb >> 4;
  u16* C = sel == 0 ? Cq : (sel == 1 ? Ck : Cv);
  const int n0 = (nb & 15) * 128;               // output col base
  const int tid = threadIdx.x;
  const int w = tid >> 6, l = tid & 63;
  const int lane15 = l & 15, quad = l >> 4;
  const int wm = (w >> 1) * 64, wn = (w & 1) * 64;
  const int srow = w * 32 + (l >> 2);
  const int skoff = (((l & 3) ^ ((l >> 3) & 3))) * 8;  // pre-swizzled chunk
  const u16* gA = A + (size_t)(m0 + srow) * K + skoff;
  const u16* gB = Bt + (size_t)(n0g + srow) * K + skoff;
  u16* lA = &As[w * 1024];  // wave-uniform LDS bases
  u16* lB = &Bs[w * 1024];
  const int rq = (quad ^ ((lane15 >> 1) & 3)) * 8;  // swizzled read chunk
  f32x4 acc[4][4] = {};
  const int nK = K >> 5;
  for (int kb = 0; kb < nK; ++kb) {
    __syncthreads();
    gld_lds16(gA, lA);
    gld_lds16(gA + (size_t)16 * K, lA + 512);
    gld_lds16(gB, lB);
    gld_lds16(gB + (size_t)16 * K, lB + 512);
    __syncthreads();
    bf16x8 af[4], bfr[4];
#pragma unroll
    for (int mi = 0; mi < 4; ++mi)
      af[mi] = *(const bf16x8*)&As[(wm + mi * 16 + lane15) * 32 + rq];
#pragma unroll
    for (int ni = 0; ni < 4; ++ni)
      bfr[ni] = *(const bf16x8*)&Bs[(wn + ni * 16 + lane15) * 32 + rq];
#pragma unroll
    for (int mi = 0; mi < 4; ++mi)
#pragma unroll
      for (int ni = 0; ni < 4; ++ni)
        acc[mi][ni] = __builtin_amdgcn_mfma_f32_16x16x32_bf16(
            af[mi], bfr[ni], acc[mi][ni], 0, 0, 0);
    gA += 32;
    gB += 32;
  }
#pragma unroll
  for (int mi = 0; mi < 4; ++mi)
#pragma unroll
    for (int ni = 0; ni < 4; ++ni)
#pragma unroll
      for (int r = 0; r < 4; ++r)
        C[(size_t)(m0 + wm + mi * 16 + quad * 4 + r) * 2048 +
          (n0 + wn + ni * 16 + lane15)] = f2b(acc[mi][ni][r]);
}

// ---------------------------------------------------------------- GEMM (fp32 out)
// Final projection: C(4096x2048 fp32) = A * Bt^T. Flat 512-block grid with
// XCD slab mapping (xcd owns 2 n-blocks -> 1 MB B set, L2-resident).
__global__ __launch_bounds__(256) void gemm_bt_f32(
    const u16* __restrict__ A, const u16* __restrict__ Bt,
    float* __restrict__ C, int K) {
  __shared__ __align__(16) u16 As[128 * 32];
  __shared__ __align__(16) u16 Bs[128 * 32];
  const int bid = blockIdx.x;
  const int xcd = bid & 7, lid = bid >> 3;      // lid in [0,64)
  const int mb = lid >> 1, nsub = lid & 1;
  const int nb = xcd * 2 + nsub;                // [0,16)
  const int m0 = mb * 128, n0 = nb * 128;
  const int tid = threadIdx.x;
  const int w = tid >> 6, l = tid & 63;
  const int lane15 = l & 15, quad = l >> 4;
  const int wm = (w >> 1) * 64, wn = (w & 1) * 64;
  const int srow = w * 32 + (l >> 2);
  const int skoff = (((l & 3) ^ ((l >> 3) & 3))) * 8;
  const u16* gA = A + (size_t)(m0 + srow) * K + skoff;
  const u16* gB = Bt + (size_t)(n0 + srow) * K + skoff;
  u16* lA = &As[w * 1024];
  u16* lB = &Bs[w * 1024];
  const int rq = (quad ^ ((lane15 >> 1) & 3)) * 8;
  f32x4 acc[4][4] = {};
  const int nK = K >> 5;
  for (int kb = 0; kb < nK; ++kb) {
    __syncthreads();
    gld_lds16(gA, lA);
    gld_lds16(gA + (size_t)16 * K, lA + 512);
    gld_lds16(gB, lB);
    gld_lds16(gB + (size_t)16 * K, lB + 512);
    __syncthreads();
    bf16x8 af[4], bfr[4];
#pragma unroll
    for (int mi = 0; mi < 4; ++mi)
      af[mi] = *(const bf16x8*)&As[(wm + mi * 16 + lane15) * 32 + rq];
#pragma unroll
    for (int ni = 0; ni < 4; ++ni)
      bfr[ni] = *(const bf16x8*)&Bs[(wn + ni * 16 + lane15) * 32 + rq];
#pragma unroll
    for (int mi = 0; mi < 4; ++mi)
#pragma unroll
      for (int ni = 0; ni < 4; ++ni)
        acc[mi][ni] = __builtin_amdgcn_mfma_f32_16x16x32_bf16(
            af[mi], bfr[ni], acc[mi][ni], 0, 0, 0);
    gA += 32;
    gB += 32;
  }
#pragma unroll
  for (int mi = 0; mi < 4; ++mi)
#pragma unroll
    for (int ni = 0; ni < 4; ++ni)
#pragma unroll
      for (int r = 0; r < 4; ++r)
        C[(size_t)(m0 + wm + mi * 16 + quad * 4 + r) * 2048 +
          (n0 + wn + ni * 16 + lane15)] = acc[mi][ni][r];
}

// ---------------------------------------------------------------- RMSNorm+RoPE
__global__ __launch_bounds__(256) void rms_rope(
    const u16* __restrict__ in, const u16* __restrict__ gamma,
    u16* __restrict__ outr) {
  const int wid = blockIdx.x * 4 + (threadIdx.x >> 6);
  const int l = threadIdx.x & 63;
  const int n = wid >> 4;
  const int h = wid & 15;
  const u16* base = in + (size_t)n * 2048 + h * 128;
  float a = b2f(base[l]), b = b2f(base[l + 64]);
  float ssum = a * a + b * b;
#pragma unroll
  for (int m = 1; m < 64; m <<= 1) ssum += __shfl_xor(ssum, m);
  const float r = rsqrtf(ssum * (1.0f / 128.0f) + 1e-6f);
  a *= r * b2f(gamma[l]);
  b *= r * b2f(gamma[l + 64]);
  const float inv = __expf(-(float)l * 0.14391156831212787f);  // 10000^(-l/64)
  float s, c;
  sincosf((float)n * inv, &s, &c);
  const size_t o = ((size_t)h * 4096 + n) * 128 + l;
  outr[o] = f2b(a * c - b * s);
  outr[o + 64] = f2b(b * c + a * s);
}

// ---------------------------------------------------------------- flash attn
// causal, BM=128 q/block, BN=64 k/iter, 8 waves (16 rows each), 512 threads.
// r8: r5/r7 showed the block-level structure (512 blocks, BM=128, h->XCD
// pinning, 24.7MB fetch) is right but each wave's serial chain (softmax VALU
// ~2.2x its MFMA work) is uncovered at ~4 waves/CU. Keep grid/L2 structure
// EXACTLY (r6's lesson: more blocks kills L2); double waves/block instead:
// 8 waves x 16 q-rows. Per-wave softmax chain halves; 2 blocks x 8 waves =
// 16 waves/CU potential. Single-buffer staging (r5's proven scheme; r7
// dbuf was neutral). LDS 48KB -> 2 blocks/CU; VGPR<=128 via
// __launch_bounds__(512,4).
__device__ __forceinline__ int swzK(int o) {  // Kt: 128 u16 per row
  return o ^ ((((o) >> 7) & 7) << 3);
}
__device__ __forceinline__ int swzV(int o) {  // Vt/Pt: 64 u16 per row
  return o ^ ((((o) >> 6) & 7) << 3);
}

__global__ __launch_bounds__(512, 4) void flash_attn(
    const u16* __restrict__ q_r, const u16* __restrict__ k_r,
    const u16* __restrict__ v_t, u16* __restrict__ attn) {
  __shared__ __align__(16) u16 Kt[64 * 128];  // [key][hd] (swizzled)
  __shared__ __align__(16) u16 Vt[128 * 64];  // [hd][key] (swizzled)
  __shared__ __align__(16) u16 Pt[128 * 64];  // [q][key]  (swizzled)
  const int b = blockIdx.x;
  const int h = b & 15;
  const int qt = (b < 256) ? (31 - (b >> 4)) : ((b - 256) >> 4);
  const int m0 = qt * 128;
  const int tid = threadIdx.x, w = tid >> 6, l = tid & 63;
  const int lane15 = l & 15, quad = l >> 4;

  bf16x8 aq[4];
#pragma unroll
  for (int ks = 0; ks < 4; ++ks)
    aq[ks] = *(const bf16x8*)&q_r[((size_t)h * 4096 + m0 + w * 16 + lane15) *
                                      128 +
                                  ks * 32 + quad * 8];

  f32x4 acc_o[8] = {};
  float m_i[4], l_i[4];
#pragma unroll
  for (int r = 0; r < 4; ++r) {
    m_i[r] = NEGINF;
    l_i[r] = 0.f;
  }

  // staging geometry (per-lane, loop-invariant); 16 row-groups, 8 waves x2
  const int keyr0 = (l >> 4);  // + rg*4
  const int kc = (l & 15);     // ^ (keyr&7), *8
  const int dr0 = (l >> 3);    // + rg*8
  const int vc = (l & 7);      // ^ (dr&7), *8

  const int jend = m0 + 64;
  for (int j0 = 0; j0 <= jend; j0 += 64) {
    __syncthreads();  // A: all waves done reading prev tile's LDS
#pragma unroll
    for (int i = 0; i < 2; ++i) {
      const int rg = i * 8 + w;  // 16 row-groups of 512 u16
      const int keyr = rg * 4 + keyr0;
      const int dr = rg * 8 + dr0;
      gld_lds16(
          &k_r[((size_t)h * 4096 + j0 + keyr) * 128 + (kc ^ (keyr & 7)) * 8],
          &Kt[rg * 512]);
      gld_lds16(&v_t[((size_t)h * 128 + dr) * 4096 + j0 + (vc ^ (dr & 7)) * 8],
                &Vt[rg * 512]);
    }
    __syncthreads();  // B: drains vmcnt -> LDS tile ready

    // S = Q K^T
    f32x4 s2[4] = {};
#pragma unroll
    for (int ni = 0; ni < 4; ++ni) {
#pragma unroll
      for (int ks = 0; ks < 4; ++ks) {
        bf16x8 bk = *(const bf16x8*)&Kt[swzK((ni * 16 + lane15) * 128 +
                                             ks * 32 + quad * 8)];
        s2[ni] = __builtin_amdgcn_mfma_f32_16x16x32_bf16(aq[ks], bk, s2[ni], 0,
                                                         0, 0);
      }
    }

    const float sc = 0.08838834764831845f;  // 1/sqrt(128)
    const bool mt = (j0 >= m0);
#pragma unroll
    for (int r = 0; r < 4; ++r) {
      const int lrow = w * 16 + quad * 4 + r;
      float xv[4], mx4 = NEGINF;
#pragma unroll
      for (int ni = 0; ni < 4; ++ni) {
        float xx = s2[ni][r] * sc;
        if (mt && (j0 + ni * 16 + lane15 > m0 + lrow)) xx = NEGINF;
        xv[ni] = xx;
        mx4 = fmaxf(mx4, xx);
      }
      const float mold = m_i[r];
      // defer-max (T13, THR=8): rescale only if a lane in this 16-lane
      // row group exceeds mold+8 (exp then bounded by e^8).
      const unsigned long long bal = __ballot(mx4 > mold + 8.0f);
      float mcur = mold;
      if (((unsigned)(bal >> (quad * 16)) & 0xFFFFu) != 0u) {
        float mx = mx4;
#pragma unroll
        for (int mk = 1; mk < 16; mk <<= 1) mx = fmaxf(mx, __shfl_xor(mx, mk));
        const float mnew = fmaxf(mold, mx);
        const float alpha = __expf(mold - mnew);
        l_i[r] *= alpha;
        m_i[r] = mnew;
        mcur = mnew;
#pragma unroll
        for (int ni = 0; ni < 8; ++ni) acc_o[ni][r] *= alpha;
      }
      float rs = 0.f;
#pragma unroll
      for (int ni = 0; ni < 4; ++ni) {
        const float p = __expf(xv[ni] - mcur);
        Pt[swzV(lrow * 64 + ni * 16 + lane15)] = f2b(p);
        rs += p;
      }
      l_i[r] += rs;  // per-lane partial; group-reduced in epilogue
    }
    // no barrier: Pt rows are same-wave (written & read by wave w only)

    // O += P V
#pragma unroll
    for (int ks = 0; ks < 2; ++ks) {
      bf16x8 ap = *(const bf16x8*)&Pt[swzV((w * 16 + lane15) * 64 + ks * 32 +
                                           quad * 8)];
#pragma unroll
      for (int ni = 0; ni < 8; ++ni) {
        bf16x8 bv = *(const bf16x8*)&Vt[swzV((ni * 16 + lane15) * 64 +
                                             ks * 32 + quad * 8)];
        acc_o[ni] =
            __builtin_amdgcn_mfma_f32_16x16x32_bf16(ap, bv, acc_o[ni], 0, 0, 0);
      }
    }
  }

  // epilogue: finish the deferred l_i group-reduction, then normalize+store
#pragma unroll
  for (int r = 0; r < 4; ++r) {
    float s = l_i[r];
#pragma unroll
    for (int mk = 1; mk < 16; mk <<= 1) s += __shfl_xor(s, mk);
    l_i[r] = s;
  }
#pragma unroll
  for (int ni = 0; ni < 8; ++ni)
#pragma unroll
    for (int r = 0; r < 4; ++r)
      attn[(size_t)(m0 + w * 16 + quad * 4 + r) * 2048 + h * 128 + ni * 16 +
           lane15] = f2b(acc_o[ni][r] / l_i[r]);
}

// ---------------------------------------------------------------- launch
// ws (58.72 MB, proven safe in r6):
//   A0 [0,16.8M):    xb      -> q_r
//   A1 [16.8,33.6M): k_buf   -> attn
//   A2 [33.6,58.72M): wT (6144x2048, 25.2M) -> v_t [33.6,50.3) + woT [50.3,58.72)
//   flags/gammas at 58.72M
// d_out (fp32, 33.5 MB):
//   D0 [0,16.8M):    q_buf   -> k_r      (dead before final gemm writes)
//   D1 [16.8,33.5M): v_buf               (dead before final gemm writes)
// Final gemm reads only ws -> no read/write race on d_out.
extern "C" void kernel_launch(void* const* d_in, const int* in_sizes, int n_in,
                              void* d_out, int out_size, void* d_ws,
                              size_t ws_size, hipStream_t stream) {
  (void)out_size; (void)ws_size;
  int ix = 0, iwq = 1, iwo = 2, ig1 = 3, ig2 = 4;
  {
    int g1 = -1, g2 = -1, xx = -1, wqq = -1, woo = -1;
    for (int i = 0; i < n_in; ++i) {
      const int s = in_sizes[i];
      if (s == 8388608) xx = i;
      else if (s == 12582912) wqq = i;
      else if (s == 4194304) woo = i;
      else if (s == 128) { if (g1 < 0) g1 = i; else g2 = i; }
    }
    if (xx >= 0 && wqq >= 0 && woo >= 0 && g1 >= 0 && g2 >= 0) {
      ix = xx; iwq = wqq; iwo = woo; ig1 = g1; ig2 = g2;
    }
  }
  const void* x = d_in[ix];
  const void* wq = d_in[iwq];
  const void* wo = d_in[iwo];
  const void* qg = d_in[ig1];
  const void* kg = d_in[ig2];
  float* out = (float*)d_out;
  char* ws = (char*)d_ws;
  u16* xb = (u16*)(ws);
  u16* k_buf = (u16*)(ws + 16777216LL);
  u16* wT = (u16*)(ws + 33554432LL);    // 6144x2048
  int* flags = (int*)(ws + 58720256LL);
  u16* gq_b = (u16*)(ws + 58720512LL);
  u16* gk_b = (u16*)(ws + 58721024LL);
  u16* q_r = (u16*)(ws);                // over dead xb
  u16* attn = (u16*)(ws + 16777216LL);  // over dead k_buf
  u16* v_t = (u16*)(ws + 33554432LL);   // over dead wT (first 16.8M)
  u16* woT = (u16*)(ws + 50331648LL);   // over dead wT (last 8.4M)
  u16* q_buf = (u16*)d_out;             // D0
  u16* k_r = (u16*)d_out;               // D0 (after q_buf dead)
  u16* v_buf = (u16*)d_out + 8388608;   // D1

  sniff5<<<5, 256, 0, stream>>>((const u16*)x, (const u16*)wq, (const u16*)wo,
                                (const u16*)qg, (const u16*)kg, flags);
  conv_in<<<8192, 256, 0, stream>>>(x, xb, flags, 0, 4096 * 2048);
  conv_in<<<1, 256, 0, stream>>>(qg, gq_b, flags, 3, 128);
  conv_in<<<1, 256, 0, stream>>>(kg, gk_b, flags, 4, 128);
  // wq^T: (2048x6144) -> wT (6144x2048)
  transpose_in<<<dim3(96, 32), 256, 0, stream>>>(wq, wT, flags, 1, 6144, 2048);
  // fused q/k/v projection: one 4096x6144 GEMM, 1536 blocks (6/CU demanded)
  gemm_qkv<<<dim3(1536), 256, 0, stream>>>(xb, wT, q_buf, k_buf, v_buf, 2048);
  // rmsnorm + rope + repack to (h,n,d); q_r over dead xb, k_r over dead q_buf
  rms_rope<<<dim3(16384), 256, 0, stream>>>(q_buf, gq_b, q_r);
  rms_rope<<<dim3(16384), 256, 0, stream>>>(k_buf, gk_b, k_r);
  // v -> v_t (h, d, n), over dead wT
  transpose_bf16<<<dim3(2, 64, 16), 256, 0, stream>>>(v_buf, v_t, 2048, 4096,
                                                      128LL, 524288LL);
  // w_out^T
  transpose_in<<<dim3(32, 32), 256, 0, stream>>>(wo, woT, flags, 2, 2048, 2048);
  // causal flash attention -> attn (n, 2048), over dead k_buf
  flash_attn<<<dim3(512), 512, 0, stream>>>(q_r, k_r, v_t, attn);
  // out = attn @ w_out -> fp32 d_out (reads only ws)
  gemm_bt_f32<<<dim3(512), 256, 0, stream>>>(attn, woT, out, 2048);
}

// Round 9
// 540.197 us; speedup vs baseline: 2.1866x; 2.1866x over previous
//
#include <hip/hip_runtime.h>
#include <stdint.h>

typedef short bf16x8 __attribute__((ext_vector_type(8)));
typedef float f32x4 __attribute__((ext_vector_type(4)));
typedef unsigned short u16;

__device__ __forceinline__ float b2f(u16 u) {
  return __uint_as_float(((unsigned)u) << 16);
}
__device__ __forceinline__ u16 f2b(float f) {
  unsigned u = __float_as_uint(f);
  return (u16)((u + 0x7fffu + ((u >> 16) & 1u)) >> 16);  // RNE
}

#define NEGINF (-1.0e30f)

__device__ __forceinline__ void gld_lds16(const u16* g, u16* l) {
  __builtin_amdgcn_global_load_lds(
      (const __attribute__((address_space(1))) unsigned int*)(const void*)g,
      (__attribute__((address_space(3))) unsigned int*)(void*)l, 16, 0, 0);
}

// swizzles for 64-u16 (128B) rows: XOR chunk bits with row&7. Involution.
__device__ __forceinline__ int swzV(int o) {
  return o ^ ((((o) >> 6) & 7) << 3);
}
__device__ __forceinline__ int swzK(int o) {  // 128-u16 rows
  return o ^ ((((o) >> 7) & 7) << 3);
}

// ---------------------------------------------------------------- dtype sniff
// flags[i]=1 -> input i is fp32 (detected from raw u16 stream signatures).
__global__ void sniff5(const u16* x, const u16* wq, const u16* wo,
                       const u16* qg, const u16* kg, int* flags) {
  const u16* p;
  int S;
  switch (blockIdx.x) {
    case 0: p = x;  S = 2048; break;
    case 1: p = wq; S = 2048; break;
    case 2: p = wo; S = 2048; break;
    case 3: p = qg; S = 128;  break;
    default: p = kg; S = 128; break;
  }
  __shared__ int cbig, czero;
  if (threadIdx.x == 0) { cbig = 0; czero = 0; }
  __syncthreads();
  int cb = 0, cz = 0;
  for (int i = threadIdx.x; i < S; i += 256) {
    const u16 u = p[i];
    if (((u >> 7) & 0xFF) >= 0xC0) ++cb;
    if (!(i & 1) && u == 0) ++cz;
  }
  atomicAdd(&cbig, cb);
  atomicAdd(&czero, cz);
  __syncthreads();
  if (threadIdx.x == 0)
    flags[blockIdx.x] = (cbig > S / 32 || czero > 3 * S / 8) ? 1 : 0;
}

// ---------------------------------------------------------------- convert
__global__ __launch_bounds__(256) void conv_in(const void* __restrict__ src,
                                               u16* __restrict__ dst,
                                               const int* __restrict__ flags,
                                               int fidx, int n) {
  const int fp32 = flags[fidx];
  int i = blockIdx.x * 256 + threadIdx.x;
  const int stride = gridDim.x * 256;
  if (fp32) {
    const float* s = (const float*)src;
    for (; i < n; i += stride) dst[i] = f2b(s[i]);
  } else {
    const u16* s = (const u16*)src;
    for (; i < n; i += stride) dst[i] = s[i];
  }
}

// ---------------------------------------------------------------- transpose_in
// dst[c][r] = bf16(src[r*ss + c]); dual-dtype. 64x64 tiles.
__global__ __launch_bounds__(256) void transpose_in(
    const void* __restrict__ src, u16* __restrict__ dst,
    const int* __restrict__ flags, int fidx, int ss, int ds) {
  __shared__ u16 tile[64][65];
  const int fp32 = flags[fidx];
  const int rb = blockIdx.y * 64, cb = blockIdx.x * 64;
  const int cl = threadIdx.x & 63, r0 = threadIdx.x >> 6;
  if (fp32) {
    const float* s = (const float*)src;
#pragma unroll
    for (int i = 0; i < 16; ++i) {
      int r = r0 + i * 4;
      tile[r][cl] = f2b(s[(long long)(rb + r) * ss + cb + cl]);
    }
  } else {
    const u16* s = (const u16*)src;
#pragma unroll
    for (int i = 0; i < 16; ++i) {
      int r = r0 + i * 4;
      tile[r][cl] = s[(long long)(rb + r) * ss + cb + cl];
    }
  }
  __syncthreads();
#pragma unroll
  for (int i = 0; i < 16; ++i) {
    int r2 = r0 + i * 4;
    dst[(long long)(cb + r2) * ds + rb + cl] = tile[cl][r2];
  }
}

// ---------------------------------------------------------------- transpose
__global__ __launch_bounds__(256) void transpose_bf16(
    const u16* __restrict__ src, u16* __restrict__ dst, int ss, int ds,
    long long sz, long long dz) {
  __shared__ u16 tile[64][65];
  const u16* s = src + (long long)blockIdx.z * sz;
  u16* d = dst + (long long)blockIdx.z * dz;
  const int rb = blockIdx.y * 64, cb = blockIdx.x * 64;
  const int cl = threadIdx.x & 63, r0 = threadIdx.x >> 6;
#pragma unroll
  for (int i = 0; i < 16; ++i) {
    int r = r0 + i * 4;
    tile[r][cl] = s[(long long)(rb + r) * ss + cb + cl];
  }
  __syncthreads();
#pragma unroll
  for (int i = 0; i < 16; ++i) {
    int r2 = r0 + i * 4;
    d[(long long)(cb + r2) * ds + rb + cl] = tile[cl][r2];
  }
}

// ---------------------------------------------------------------- fused QKV GEMM
// C(4096 x 6144) = A(4096x2048) * Bt(6144x2048)^T -> q/k/v (each ldc 2048).
// r9: BK 32->64 (halves barrier count 64->32; barrier vmcnt-drain is the
// m97-structure's known stall). LDS rows are 64 u16 (128B) -> Vt-style XOR
// swizzle: staging pre-swizzles the global chunk (c ^ (row&7), lane-static
// since row&7 = l>>3), reads apply swzV. K-step processed as two kk
// sub-slices with reused fragment regs -> register peak unchanged.
// XCD slab mapping unchanged (xcd=bid&7 owns 6 n-blocks, B L2-resident).
__global__ __launch_bounds__(256) void gemm_qkv(
    const u16* __restrict__ A, const u16* __restrict__ Bt,
    u16* __restrict__ Cq, u16* __restrict__ Ck, u16* __restrict__ Cv, int K) {
  __shared__ __align__(16) u16 As[128 * 64];
  __shared__ __align__(16) u16 Bs[128 * 64];
  const int bid = blockIdx.x;
  const int xcd = bid & 7, lid = bid >> 3;      // lid in [0,192)
  const int mb = lid / 6, nsub = lid - mb * 6;  // mb [0,32), nsub [0,6)
  const int nb = xcd * 6 + nsub;                // [0,48)
  const int m0 = mb * 128;
  const int n0g = nb * 128;                     // Bt row base (0..6143)
  const int sel = nb >> 4;
  u16* C = sel == 0 ? Cq : (sel == 1 ? Ck : Cv);
  const int n0 = (nb & 15) * 128;               // output col base
  const int tid = threadIdx.x;
  const int w = tid >> 6, l = tid & 63;
  const int lane15 = l & 15, quad = l >> 4;
  const int wm = (w >> 1) * 64, wn = (w & 1) * 64;
  // staging: group g = i*4+w covers rows 8g..8g+7; lane l -> row 8g+(l>>3),
  // chunk l&7; global chunk pre-swizzled by ^(l>>3).
  const int r8 = l >> 3, c8 = l & 7;
  const int sk = (c8 ^ r8) * 8;
  const u16* gA = A + (size_t)(m0 + r8) * K + sk;
  const u16* gB = Bt + (size_t)(n0g + r8) * K + sk;
  f32x4 acc[4][4] = {};
  const int nK = K >> 6;
  for (int kb = 0; kb < nK; ++kb) {
    __syncthreads();  // WAR: previous iter's readers done
#pragma unroll
    for (int i = 0; i < 4; ++i) {
      const int g = i * 4 + w;
      gld_lds16(gA + (size_t)g * 8 * K, &As[g * 512]);
      gld_lds16(gB + (size_t)g * 8 * K, &Bs[g * 512]);
    }
    __syncthreads();  // drains vmcnt -> tile ready
#pragma unroll
    for (int kk = 0; kk < 2; ++kk) {
      bf16x8 af[4], bfr[4];
#pragma unroll
      for (int mi = 0; mi < 4; ++mi)
        af[mi] = *(const bf16x8*)&As[swzV((wm + mi * 16 + lane15) * 64 +
                                          kk * 32 + quad * 8)];
#pragma unroll
      for (int ni = 0; ni < 4; ++ni)
        bfr[ni] = *(const bf16x8*)&Bs[swzV((wn + ni * 16 + lane15) * 64 +
                                           kk * 32 + quad * 8)];
#pragma unroll
      for (int mi = 0; mi < 4; ++mi)
#pragma unroll
        for (int ni = 0; ni < 4; ++ni)
          acc[mi][ni] = __builtin_amdgcn_mfma_f32_16x16x32_bf16(
              af[mi], bfr[ni], acc[mi][ni], 0, 0, 0);
    }
    gA += 64;
    gB += 64;
  }
#pragma unroll
  for (int mi = 0; mi < 4; ++mi)
#pragma unroll
    for (int ni = 0; ni < 4; ++ni)
#pragma unroll
      for (int r = 0; r < 4; ++r)
        C[(size_t)(m0 + wm + mi * 16 + quad * 4 + r) * 2048 +
          (n0 + wn + ni * 16 + lane15)] = f2b(acc[mi][ni][r]);
}

// ---------------------------------------------------------------- GEMM (fp32 out)
// Final projection: C(4096x2048 fp32) = A * Bt^T. BK=64 (same as gemm_qkv).
// 512 blocks with XCD slab mapping (xcd owns 2 n-blocks, 1 MB B L2-set).
__global__ __launch_bounds__(256) void gemm_bt_f32(
    const u16* __restrict__ A, const u16* __restrict__ Bt,
    float* __restrict__ C, int K) {
  __shared__ __align__(16) u16 As[128 * 64];
  __shared__ __align__(16) u16 Bs[128 * 64];
  const int bid = blockIdx.x;
  const int xcd = bid & 7, lid = bid >> 3;      // lid in [0,64)
  const int mb = lid >> 1, nsub = lid & 1;
  const int nb = xcd * 2 + nsub;                // [0,16)
  const int m0 = mb * 128, n0 = nb * 128;
  const int tid = threadIdx.x;
  const int w = tid >> 6, l = tid & 63;
  const int lane15 = l & 15, quad = l >> 4;
  const int wm = (w >> 1) * 64, wn = (w & 1) * 64;
  const int r8 = l >> 3, c8 = l & 7;
  const int sk = (c8 ^ r8) * 8;
  const u16* gA = A + (size_t)(m0 + r8) * K + sk;
  const u16* gB = Bt + (size_t)(n0 + r8) * K + sk;
  f32x4 acc[4][4] = {};
  const int nK = K >> 6;
  for (int kb = 0; kb < nK; ++kb) {
    __syncthreads();
#pragma unroll
    for (int i = 0; i < 4; ++i) {
      const int g = i * 4 + w;
      gld_lds16(gA + (size_t)g * 8 * K, &As[g * 512]);
      gld_lds16(gB + (size_t)g * 8 * K, &Bs[g * 512]);
    }
    __syncthreads();
#pragma unroll
    for (int kk = 0; kk < 2; ++kk) {
      bf16x8 af[4], bfr[4];
#pragma unroll
      for (int mi = 0; mi < 4; ++mi)
        af[mi] = *(const bf16x8*)&As[swzV((wm + mi * 16 + lane15) * 64 +
                                          kk * 32 + quad * 8)];
#pragma unroll
      for (int ni = 0; ni < 4; ++ni)
        bfr[ni] = *(const bf16x8*)&Bs[swzV((wn + ni * 16 + lane15) * 64 +
                                           kk * 32 + quad * 8)];
#pragma unroll
      for (int mi = 0; mi < 4; ++mi)
#pragma unroll
        for (int ni = 0; ni < 4; ++ni)
          acc[mi][ni] = __builtin_amdgcn_mfma_f32_16x16x32_bf16(
              af[mi], bfr[ni], acc[mi][ni], 0, 0, 0);
    }
    gA += 64;
    gB += 64;
  }
#pragma unroll
  for (int mi = 0; mi < 4; ++mi)
#pragma unroll
    for (int ni = 0; ni < 4; ++ni)
#pragma unroll
      for (int r = 0; r < 4; ++r)
        C[(size_t)(m0 + wm + mi * 16 + quad * 4 + r) * 2048 +
          (n0 + wn + ni * 16 + lane15)] = acc[mi][ni][r];
}

// ---------------------------------------------------------------- RMSNorm+RoPE
__global__ __launch_bounds__(256) void rms_rope(
    const u16* __restrict__ in, const u16* __restrict__ gamma,
    u16* __restrict__ outr) {
  const int wid = blockIdx.x * 4 + (threadIdx.x >> 6);
  const int l = threadIdx.x & 63;
  const int n = wid >> 4;
  const int h = wid & 15;
  const u16* base = in + (size_t)n * 2048 + h * 128;
  float a = b2f(base[l]), b = b2f(base[l + 64]);
  float ssum = a * a + b * b;
#pragma unroll
  for (int m = 1; m < 64; m <<= 1) ssum += __shfl_xor(ssum, m);
  const float r = rsqrtf(ssum * (1.0f / 128.0f) + 1e-6f);
  a *= r * b2f(gamma[l]);
  b *= r * b2f(gamma[l + 64]);
  const float inv = __expf(-(float)l * 0.14391156831212787f);  // 10000^(-l/64)
  float s, c;
  sincosf((float)n * inv, &s, &c);
  const size_t o = ((size_t)h * 4096 + n) * 128 + l;
  outr[o] = f2b(a * c - b * s);
  outr[o + 64] = f2b(b * c + a * s);
}

// ---------------------------------------------------------------- flash attn
// EXACT r5 kernel (measured 205.8 us, FETCH 24.7MB): causal, BM=128, BN=64,
// 4 waves x 32 rows, 256 threads, launch_bounds(256,2). This sits at the
// L2-locality equilibrium: ~32 phase-aligned blocks/XCD share one K/V
// stream. r6 (grid x2), r7 (dbuf pipeline), r8 (8 waves) all failed to beat
// it -- raising residency decorrelates j0 phases and thrashes L2
// (tile-granular eviction traffic = 32KB x total-iters, measured exactly).
// FROZEN: do not raise occupancy without re-deriving XCD residency.
__global__ __launch_bounds__(256, 2) void flash_attn(
    const u16* __restrict__ q_r, const u16* __restrict__ k_r,
    const u16* __restrict__ v_t, u16* __restrict__ attn) {
  __shared__ __align__(16) u16 Kt[64 * 128];  // [key][hd] (swizzled)
  __shared__ __align__(16) u16 Vt[128 * 64];  // [hd][key] (swizzled)
  __shared__ __align__(16) u16 Pt[128 * 64];  // [q][key]  (swizzled)
  const int b = blockIdx.x;
  const int h = b & 15;
  const int qt = (b < 256) ? (31 - (b >> 4)) : ((b - 256) >> 4);
  const int m0 = qt * 128;
  const int tid = threadIdx.x, w = tid >> 6, l = tid & 63;
  const int lane15 = l & 15, quad = l >> 4;

  bf16x8 aq[2][4];
#pragma unroll
  for (int mi = 0; mi < 2; ++mi)
#pragma unroll
    for (int ks = 0; ks < 4; ++ks)
      aq[mi][ks] = *(const bf16x8*)&q_r[((size_t)h * 4096 + m0 + w * 32 +
                                         mi * 16 + lane15) * 128 +
                                        ks * 32 + quad * 8];

  f32x4 acc_o[2][8] = {};
  float m_i[2][4], l_i[2][4];
#pragma unroll
  for (int mi = 0; mi < 2; ++mi)
#pragma unroll
    for (int r = 0; r < 4; ++r) {
      m_i[mi][r] = NEGINF;
      l_i[mi][r] = 0.f;
    }

  const int jend = m0 + 64;
  for (int j0 = 0; j0 <= jend; j0 += 64) {
    __syncthreads();  // A: all waves done reading prev tile's LDS
#pragma unroll
    for (int i = 0; i < 4; ++i) {
      const int rg = i * 4 + w;             // 16 row-groups of 512 u16
      const int keyr = rg * 4 + (l >> 4);   // K tile row (0..63)
      const int kc = (l & 15) ^ (keyr & 7); // pre-swizzled 16B chunk
      const int dr = rg * 8 + (l >> 3);     // V tile row d (0..127)
      const int vc = (l & 7) ^ (dr & 7);
      gld_lds16(&k_r[((size_t)h * 4096 + j0 + keyr) * 128 + kc * 8],
                &Kt[rg * 512]);
      gld_lds16(&v_t[((size_t)h * 128 + dr) * 4096 + j0 + vc * 8],
                &Vt[rg * 512]);
    }
    __syncthreads();  // B: drains vmcnt -> LDS tile ready

    // S = Q K^T
    f32x4 s2[2][4] = {};
#pragma unroll
    for (int ni = 0; ni < 4; ++ni) {
#pragma unroll
      for (int ks = 0; ks < 4; ++ks) {
        bf16x8 bk = *(const bf16x8*)&Kt[swzK((ni * 16 + lane15) * 128 +
                                             ks * 32 + quad * 8)];
        s2[0][ni] = __builtin_amdgcn_mfma_f32_16x16x32_bf16(aq[0][ks], bk,
                                                            s2[0][ni], 0, 0, 0);
        s2[1][ni] = __builtin_amdgcn_mfma_f32_16x16x32_bf16(aq[1][ks], bk,
                                                            s2[1][ni], 0, 0, 0);
      }
    }

    const float sc = 0.08838834764831845f;  // 1/sqrt(128)
    const bool mt = (j0 >= m0);
#pragma unroll
    for (int mi = 0; mi < 2; ++mi) {
#pragma unroll
      for (int r = 0; r < 4; ++r) {
        const int lrow = w * 32 + mi * 16 + quad * 4 + r;
        float xv[4], mx4 = NEGINF;
#pragma unroll
        for (int ni = 0; ni < 4; ++ni) {
          float xx = s2[mi][ni][r] * sc;
          if (mt && (j0 + ni * 16 + lane15 > m0 + lrow)) xx = NEGINF;
          xv[ni] = xx;
          mx4 = fmaxf(mx4, xx);
        }
        const float mold = m_i[mi][r];
        // defer-max (T13, THR=8): rescale only if a lane in this 16-lane
        // row group exceeds mold+8 (exp then bounded by e^8).
        const unsigned long long bal = __ballot(mx4 > mold + 8.0f);
        float mcur = mold;
        if (((unsigned)(bal >> (quad * 16)) & 0xFFFFu) != 0u) {
          float mx = mx4;
#pragma unroll
          for (int mk = 1; mk < 16; mk <<= 1)
            mx = fmaxf(mx, __shfl_xor(mx, mk));
          const float mnew = fmaxf(mold, mx);
          const float alpha = __expf(mold - mnew);
          l_i[mi][r] *= alpha;
          m_i[mi][r] = mnew;
          mcur = mnew;
#pragma unroll
          for (int ni = 0; ni < 8; ++ni) acc_o[mi][ni][r] *= alpha;
        }
        float rs = 0.f;
#pragma unroll
        for (int ni = 0; ni < 4; ++ni) {
          const float p = __expf(xv[ni] - mcur);
          Pt[swzV(lrow * 64 + ni * 16 + lane15)] = f2b(p);
          rs += p;
        }
        l_i[mi][r] += rs;  // per-lane partial; group-reduced in epilogue
      }
    }
    // no barrier: Pt rows are same-wave (written & read by wave w only)

    // O += P V
#pragma unroll
    for (int ks = 0; ks < 2; ++ks) {
      bf16x8 ap0 = *(const bf16x8*)&Pt[swzV((w * 32 + lane15) * 64 + ks * 32 +
                                            quad * 8)];
      bf16x8 ap1 = *(const bf16x8*)&Pt[swzV((w * 32 + 16 + lane15) * 64 +
                                            ks * 32 + quad * 8)];
#pragma unroll
      for (int ni = 0; ni < 8; ++ni) {
        bf16x8 bv = *(const bf16x8*)&Vt[swzV((ni * 16 + lane15) * 64 +
                                             ks * 32 + quad * 8)];
        acc_o[0][ni] = __builtin_amdgcn_mfma_f32_16x16x32_bf16(
            ap0, bv, acc_o[0][ni], 0, 0, 0);
        acc_o[1][ni] = __builtin_amdgcn_mfma_f32_16x16x32_bf16(
            ap1, bv, acc_o[1][ni], 0, 0, 0);
      }
    }
  }

  // epilogue: finish the deferred l_i group-reduction, then normalize+store
#pragma unroll
  for (int mi = 0; mi < 2; ++mi)
#pragma unroll
    for (int r = 0; r < 4; ++r) {
      float s = l_i[mi][r];
#pragma unroll
      for (int mk = 1; mk < 16; mk <<= 1) s += __shfl_xor(s, mk);
      l_i[mi][r] = s;
    }
#pragma unroll
  for (int mi = 0; mi < 2; ++mi)
#pragma unroll
    for (int ni = 0; ni < 8; ++ni)
#pragma unroll
      for (int r = 0; r < 4; ++r)
        attn[(size_t)(m0 + w * 32 + mi * 16 + quad * 4 + r) * 2048 + h * 128 +
             ni * 16 + lane15] = f2b(acc_o[mi][ni][r] / l_i[mi][r]);
}

// ---------------------------------------------------------------- launch
// ws (58.72 MB, proven safe in r6):
//   A0 [0,16.8M):    xb      -> q_r
//   A1 [16.8,33.6M): k_buf   -> attn
//   A2 [33.6,58.72M): wT (6144x2048, 25.2M) -> v_t [33.6,50.3) + woT [50.3,58.72)
//   flags/gammas at 58.72M
// d_out (fp32, 33.5 MB):
//   D0 [0,16.8M):    q_buf   -> k_r      (dead before final gemm writes)
//   D1 [16.8,33.5M): v_buf               (dead before final gemm writes)
// Final gemm reads only ws -> no read/write race on d_out.
extern "C" void kernel_launch(void* const* d_in, const int* in_sizes, int n_in,
                              void* d_out, int out_size, void* d_ws,
                              size_t ws_size, hipStream_t stream) {
  (void)out_size; (void)ws_size;
  int ix = 0, iwq = 1, iwo = 2, ig1 = 3, ig2 = 4;
  {
    int g1 = -1, g2 = -1, xx = -1, wqq = -1, woo = -1;
    for (int i = 0; i < n_in; ++i) {
      const int s = in_sizes[i];
      if (s == 8388608) xx = i;
      else if (s == 12582912) wqq = i;
      else if (s == 4194304) woo = i;
      else if (s == 128) { if (g1 < 0) g1 = i; else g2 = i; }
    }
    if (xx >= 0 && wqq >= 0 && woo >= 0 && g1 >= 0 && g2 >= 0) {
      ix = xx; iwq = wqq; iwo = woo; ig1 = g1; ig2 = g2;
    }
  }
  const void* x = d_in[ix];
  const void* wq = d_in[iwq];
  const void* wo = d_in[iwo];
  const void* qg = d_in[ig1];
  const void* kg = d_in[ig2];
  float* out = (float*)d_out;
  char* ws = (char*)d_ws;
  u16* xb = (u16*)(ws);
  u16* k_buf = (u16*)(ws + 16777216LL);
  u16* wT = (u16*)(ws + 33554432LL);    // 6144x2048
  int* flags = (int*)(ws + 58720256LL);
  u16* gq_b = (u16*)(ws + 58720512LL);
  u16* gk_b = (u16*)(ws + 58721024LL);
  u16* q_r = (u16*)(ws);                // over dead xb
  u16* attn = (u16*)(ws + 16777216LL);  // over dead k_buf
  u16* v_t = (u16*)(ws + 33554432LL);   // over dead wT (first 16.8M)
  u16* woT = (u16*)(ws + 50331648LL);   // over dead wT (last 8.4M)
  u16* q_buf = (u16*)d_out;             // D0
  u16* k_r = (u16*)d_out;               // D0 (after q_buf dead)
  u16* v_buf = (u16*)d_out + 8388608;   // D1

  sniff5<<<5, 256, 0, stream>>>((const u16*)x, (const u16*)wq, (const u16*)wo,
                                (const u16*)qg, (const u16*)kg, flags);
  conv_in<<<8192, 256, 0, stream>>>(x, xb, flags, 0, 4096 * 2048);
  conv_in<<<1, 256, 0, stream>>>(qg, gq_b, flags, 3, 128);
  conv_in<<<1, 256, 0, stream>>>(kg, gk_b, flags, 4, 128);
  // wq^T: (2048x6144) -> wT (6144x2048)
  transpose_in<<<dim3(96, 32), 256, 0, stream>>>(wq, wT, flags, 1, 6144, 2048);
  // fused q/k/v projection: one 4096x6144 GEMM, 1536 blocks, BK=64
  gemm_qkv<<<dim3(1536), 256, 0, stream>>>(xb, wT, q_buf, k_buf, v_buf, 2048);
  // rmsnorm + rope + repack to (h,n,d); q_r over dead xb, k_r over dead q_buf
  rms_rope<<<dim3(16384), 256, 0, stream>>>(q_buf, gq_b, q_r);
  rms_rope<<<dim3(16384), 256, 0, stream>>>(k_buf, gk_b, k_r);
  // v -> v_t (h, d, n), over dead wT
  transpose_bf16<<<dim3(2, 64, 16), 256, 0, stream>>>(v_buf, v_t, 2048, 4096,
                                                      128LL, 524288LL);
  // w_out^T
  transpose_in<<<dim3(32, 32), 256, 0, stream>>>(wo, woT, flags, 2, 2048, 2048);
  // causal flash attention -> attn (n, 2048), over dead k_buf (r5 kernel)
  flash_attn<<<dim3(512), 256, 0, stream>>>(q_r, k_r, v_t, attn);
  // out = attn @ w_out -> fp32 d_out (reads only ws), BK=64
  gemm_bt_f32<<<dim3(512), 256, 0, stream>>>(attn, woT, out, 2048);
}